// Round 1
// baseline (1067.053 us; speedup 1.0000x reference)
//
#include <hip/hip_runtime.h>
#include <math.h>

#define NNODES 50000
#define NEDGES 800000
#define NTOT   850000   // edges + self-loops
#define NHEAD  8
#define HDIM   32
#define HHD    256      // NHEAD*HDIM
#define NCLS   40
#define NEG_SLOPE 0.2f

// ---------------- CSR build ----------------

__global__ void k_init_counts(int* __restrict__ counts) {
    int i = blockIdx.x * 256 + threadIdx.x;
    if (i < NNODES) counts[i] = 1;   // self-loop
}

__global__ void k_count(const int* __restrict__ ei, int* __restrict__ counts) {
    int i = blockIdx.x * 256 + threadIdx.x;
    if (i < NEDGES) atomicAdd(&counts[ei[NEDGES + i]], 1);  // dst row
}

__global__ __launch_bounds__(1024) void k_scan(const int* __restrict__ counts,
                                               int* __restrict__ row_ptr) {
    __shared__ int lds[1024];
    __shared__ int carry_s;
    int t = threadIdx.x;
    if (t == 0) carry_s = 0;
    __syncthreads();
    for (int base = 0; base < NNODES; base += 1024) {
        int i = base + t;
        int v = (i < NNODES) ? counts[i] : 0;
        lds[t] = v;
        __syncthreads();
        for (int off = 1; off < 1024; off <<= 1) {
            int add = (t >= off) ? lds[t - off] : 0;
            __syncthreads();
            lds[t] += add;
            __syncthreads();
        }
        int incl  = lds[t];
        int carry = carry_s;
        if (i < NNODES) row_ptr[i] = carry + incl - v;   // exclusive
        __syncthreads();
        if (t == 1023) carry_s = carry + incl;
        __syncthreads();
    }
    if (t == 0) row_ptr[NNODES] = carry_s;
}

__global__ void k_copy(const int* __restrict__ row_ptr, int* __restrict__ cursor) {
    int i = blockIdx.x * 256 + threadIdx.x;
    if (i < NNODES) cursor[i] = row_ptr[i];
}

__global__ void k_scatter(const int* __restrict__ ei, int* __restrict__ cursor,
                          int* __restrict__ esrc) {
    int i = blockIdx.x * 256 + threadIdx.x;
    if (i < NEDGES) {
        int s = ei[i];
        int d = ei[NEDGES + i];
        int pos = atomicAdd(&cursor[d], 1);
        esrc[pos] = s;
    }
}

__global__ void k_scatter_loops(int* __restrict__ cursor, int* __restrict__ esrc) {
    int i = blockIdx.x * 256 + threadIdx.x;
    if (i < NNODES) {
        int pos = atomicAdd(&cursor[i], 1);
        esrc[pos] = i;
    }
}

// ---------------- GEMM (fp32, tiled) ----------------
// C[M,Nc] = A[M,K] @ B[K,Nc] (+bias)
#define BM 64
#define BN 64
#define BK 32

__global__ __launch_bounds__(256) void k_gemm(const float* __restrict__ A,
                                              const float* __restrict__ B,
                                              const float* __restrict__ bias,
                                              float* __restrict__ C,
                                              int M, int Nc, int K) {
    __shared__ float As[BM][BK + 1];
    __shared__ float Bs[BK][BN + 4];
    int tx = threadIdx.x & 15;
    int ty = threadIdx.x >> 4;
    int rowBase = blockIdx.y * BM;
    int colBase = blockIdx.x * BN;
    float acc[4][4] = {};
    for (int k0 = 0; k0 < K; k0 += BK) {
        for (int i = threadIdx.x; i < BM * BK; i += 256) {
            int r = i >> 5, c = i & 31;            // BK == 32
            int gr = rowBase + r;
            As[r][c] = (gr < M) ? A[(size_t)gr * K + k0 + c] : 0.f;
        }
        for (int i = threadIdx.x; i < BK * BN; i += 256) {
            int r = i >> 6, c = i & 63;            // BN == 64
            int gc = colBase + c;
            Bs[r][c] = (gc < Nc) ? B[(size_t)(k0 + r) * Nc + gc] : 0.f;
        }
        __syncthreads();
        #pragma unroll
        for (int kk = 0; kk < BK; ++kk) {
            float av[4], bv[4];
            #pragma unroll
            for (int i = 0; i < 4; ++i) av[i] = As[ty * 4 + i][kk];
            #pragma unroll
            for (int j = 0; j < 4; ++j) bv[j] = Bs[kk][tx * 4 + j];
            #pragma unroll
            for (int i = 0; i < 4; ++i)
                #pragma unroll
                for (int j = 0; j < 4; ++j)
                    acc[i][j] += av[i] * bv[j];
        }
        __syncthreads();
    }
    #pragma unroll
    for (int i = 0; i < 4; ++i) {
        int gr = rowBase + ty * 4 + i;
        if (gr >= M) continue;
        #pragma unroll
        for (int j = 0; j < 4; ++j) {
            int gc = colBase + tx * 4 + j;
            if (gc >= Nc) continue;
            float v = acc[i][j];
            if (bias) v += bias[gc];
            C[(size_t)gr * Nc + gc] = v;
        }
    }
}

// ---------------- per-node attention coefficients ----------------
// alpha_s[n,h] = dot(xh[n,h,:], a_src[h,:]); same for dst
__global__ void k_alpha(const float* __restrict__ xh,
                        const float* __restrict__ a_src,
                        const float* __restrict__ a_dst,
                        float* __restrict__ alpha_s,
                        float* __restrict__ alpha_d) {
    int idx = blockIdx.x * 256 + threadIdx.x;   // n*8 + h
    if (idx < NNODES * NHEAD) {
        int node = idx >> 3, h = idx & 7;
        const float* p = xh + (size_t)node * HHD + h * HDIM;
        float ss = 0.f, sd = 0.f;
        #pragma unroll
        for (int d = 0; d < HDIM; ++d) {
            float v = p[d];
            ss += v * a_src[h * HDIM + d];
            sd += v * a_dst[h * HDIM + d];
        }
        alpha_s[idx] = ss;
        alpha_d[idx] = sd;
    }
}

// ---------------- GAT aggregation (block per dst node) ----------------
__global__ __launch_bounds__(256) void k_agg(const float* __restrict__ xh,
                                             const float* __restrict__ alpha_s,
                                             const float* __restrict__ alpha_d,
                                             const int* __restrict__ row_ptr,
                                             const int* __restrict__ esrc,
                                             const float* __restrict__ bias,
                                             float* __restrict__ out) {
    int node = blockIdx.x;
    int t = threadIdx.x;          // 256 threads: t = h*32 + d
    int h = t >> 5;
    int beg = row_ptr[node], end = row_ptr[node + 1];
    float ad = alpha_d[node * NHEAD + h];

    // pass 1: per-head max of leaky(e)
    float m = -1e30f;
    for (int i = beg; i < end; ++i) {
        int s = esrc[i];
        float e = alpha_s[s * NHEAD + h] + ad;
        e = (e > 0.f) ? e : NEG_SLOPE * e;
        m = fmaxf(m, e);
    }
    // pass 2: exp-sum + weighted accumulate
    float acc = 0.f, ssum = 0.f;
    for (int i = beg; i < end; ++i) {
        int s = esrc[i];
        float e = alpha_s[s * NHEAD + h] + ad;
        e = (e > 0.f) ? e : NEG_SLOPE * e;
        float p = __expf(e - m);
        ssum += p;
        acc += p * xh[(size_t)s * HHD + t];
    }
    float r = acc / ssum + bias[t];
    r = fmaxf(r, 0.f);            // both GAT layers are followed by ReLU
    out[(size_t)node * HHD + t] = r;
}

// ---------------- launch ----------------

extern "C" void kernel_launch(void* const* d_in, const int* in_sizes, int n_in,
                              void* d_out, int out_size, void* d_ws, size_t ws_size,
                              hipStream_t stream) {
    const float* x   = (const float*)d_in[0];
    const int*   ei  = (const int*)  d_in[1];
    const float* W1  = (const float*)d_in[2];
    const float* a1s = (const float*)d_in[3];
    const float* a1d = (const float*)d_in[4];
    const float* b1  = (const float*)d_in[5];
    const float* W2  = (const float*)d_in[6];
    const float* a2s = (const float*)d_in[7];
    const float* a2d = (const float*)d_in[8];
    const float* b2  = (const float*)d_in[9];
    const float* Wc  = (const float*)d_in[10];
    const float* bc  = (const float*)d_in[11];
    float* out = (float*)d_out;

    char* ws = (char*)d_ws;
    size_t off = 0;
    auto alloc = [&](size_t bytes) -> void* {
        void* p = ws + off;
        off += (bytes + 255) & ~(size_t)255;
        return p;
    };
    float* xh    = (float*)alloc((size_t)NNODES * HHD * 4);
    float* hbuf  = (float*)alloc((size_t)NNODES * HHD * 4);
    float* as_   = (float*)alloc((size_t)NNODES * NHEAD * 4);
    float* ad_   = (float*)alloc((size_t)NNODES * NHEAD * 4);
    int* counts  = (int*)alloc((size_t)NNODES * 4);
    int* row_ptr = (int*)alloc((size_t)(NNODES + 1) * 4);
    int* cursor  = (int*)alloc((size_t)NNODES * 4);
    int* esrc    = (int*)alloc((size_t)NTOT * 4);
    (void)ws_size; (void)in_sizes; (void)n_in; (void)out_size;

    int gn = (NNODES + 255) / 256;
    int ge = (NEDGES + 255) / 256;

    // CSR build (same graph for both layers)
    k_init_counts<<<gn, 256, 0, stream>>>(counts);
    k_count<<<ge, 256, 0, stream>>>(ei, counts);
    k_scan<<<1, 1024, 0, stream>>>(counts, row_ptr);
    k_copy<<<gn, 256, 0, stream>>>(row_ptr, cursor);
    k_scatter<<<ge, 256, 0, stream>>>(ei, cursor, esrc);
    k_scatter_loops<<<gn, 256, 0, stream>>>(cursor, esrc);

    dim3 gHid((HHD + BN - 1) / BN, (NNODES + BM - 1) / BM);
    dim3 gCls((NCLS + BN - 1) / BN, (NNODES + BM - 1) / BM);
    int ga = (NNODES * NHEAD + 255) / 256;

    // layer 1
    k_gemm<<<gHid, 256, 0, stream>>>(x, W1, nullptr, xh, NNODES, HHD, 128);
    k_alpha<<<ga, 256, 0, stream>>>(xh, a1s, a1d, as_, ad_);
    k_agg<<<NNODES, 256, 0, stream>>>(xh, as_, ad_, row_ptr, esrc, b1, hbuf);

    // layer 2
    k_gemm<<<gHid, 256, 0, stream>>>(hbuf, W2, nullptr, xh, NNODES, HHD, HHD);
    k_alpha<<<ga, 256, 0, stream>>>(xh, a2s, a2d, as_, ad_);
    k_agg<<<NNODES, 256, 0, stream>>>(xh, as_, ad_, row_ptr, esrc, b2, hbuf);

    // classifier
    k_gemm<<<gCls, 256, 0, stream>>>(hbuf, Wc, bc, out, NNODES, NCLS, HHD);
}

// Round 2
// 588.346 us; speedup vs baseline: 1.8136x; 1.8136x over previous
//
#include <hip/hip_runtime.h>
#include <math.h>

#define NNODES 50000
#define NEDGES 800000
#define NTOT   850000   // edges + self-loops
#define NHEAD  8
#define HDIM   32
#define HHD    256      // NHEAD*HDIM
#define NCLS   40
#define NEG_SLOPE 0.2f

// ---------------- CSR build ----------------

__global__ void k_init_counts(int* __restrict__ counts) {
    int i = blockIdx.x * 256 + threadIdx.x;
    if (i < NNODES) counts[i] = 1;   // self-loop
}

__global__ void k_count(const int* __restrict__ ei, int* __restrict__ counts) {
    int i = blockIdx.x * 256 + threadIdx.x;
    if (i < NEDGES) atomicAdd(&counts[ei[NEDGES + i]], 1);  // dst row
}

// hierarchical scan: scan1 (per-block excl scan + block sums), scan2 (scan of
// block sums, single block), scan3 (add offsets, write row_ptr + cursor)
__global__ __launch_bounds__(256) void k_scan1(const int* __restrict__ counts,
                                               int* __restrict__ partial,
                                               int* __restrict__ bsums) {
    __shared__ int lds[256];
    int t = threadIdx.x;
    int i = blockIdx.x * 256 + t;
    int v = (i < NNODES) ? counts[i] : 0;
    lds[t] = v;
    __syncthreads();
    for (int off = 1; off < 256; off <<= 1) {
        int add = (t >= off) ? lds[t - off] : 0;
        __syncthreads();
        lds[t] += add;
        __syncthreads();
    }
    if (i < NNODES) partial[i] = lds[t] - v;   // exclusive within block
    if (t == 255) bsums[blockIdx.x] = lds[255];
}

__global__ __launch_bounds__(256) void k_scan2(const int* __restrict__ bsums,
                                               int* __restrict__ boff, int nb) {
    __shared__ int lds[256];
    int t = threadIdx.x;
    int v = (t < nb) ? bsums[t] : 0;
    lds[t] = v;
    __syncthreads();
    for (int off = 1; off < 256; off <<= 1) {
        int add = (t >= off) ? lds[t - off] : 0;
        __syncthreads();
        lds[t] += add;
        __syncthreads();
    }
    if (t < nb) boff[t] = lds[t] - v;
}

__global__ void k_scan3(int* __restrict__ row_ptr, const int* __restrict__ boff,
                        int* __restrict__ cursor) {
    int i = blockIdx.x * 256 + threadIdx.x;
    if (i < NNODES) {
        int r = row_ptr[i] + boff[blockIdx.x];
        row_ptr[i] = r;
        cursor[i] = r;
    }
    if (i == 0) row_ptr[NNODES] = NTOT;   // total edge count is static
}

__global__ void k_scatter(const int* __restrict__ ei, int* __restrict__ cursor,
                          int* __restrict__ esrc) {
    int i = blockIdx.x * 256 + threadIdx.x;
    if (i < NEDGES) {
        int s = ei[i];
        int d = ei[NEDGES + i];
        int pos = atomicAdd(&cursor[d], 1);
        esrc[pos] = s;
    }
}

__global__ void k_scatter_loops(int* __restrict__ cursor, int* __restrict__ esrc) {
    int i = blockIdx.x * 256 + threadIdx.x;
    if (i < NNODES) {
        int pos = atomicAdd(&cursor[i], 1);
        esrc[pos] = i;
    }
}

// ---------------- GEMM (fp32, 128x64 tile, BK=32, LDS-transposed A) --------
#define GBM 128
#define GBN 64
#define GBK 32

__global__ __launch_bounds__(256) void k_gemm(const float* __restrict__ A,
                                              const float* __restrict__ B,
                                              const float* __restrict__ bias,
                                              float* __restrict__ C,
                                              int M, int Nc, int K) {
    __shared__ float As[GBK][132];   // transposed: As[k][m], pad for conflicts
    __shared__ float Bs[GBK][68];    // Bs[k][n]
    int t = threadIdx.x;
    int tx = t & 15;                 // col group (tx*4)
    int ty = t >> 4;                 // row group (ty*8)
    int rowBase = blockIdx.y * GBM;
    int colBase = blockIdx.x * GBN;
    float acc[8][4] = {};
    // A staging: chunk c = 4t..4t+3, row = c>>3, kq = c&7 (each thread: 1 row)
    int arow = (t * 4) >> 3;
    int akq  = (t * 4) & 7;
    int agr  = rowBase + arow;
    for (int k0 = 0; k0 < K; k0 += GBK) {
        const float* ap = A + (size_t)agr * K + k0;
        #pragma unroll
        for (int q = 0; q < 4; ++q) {
            int kq = akq + q;
            float4 v = {0.f, 0.f, 0.f, 0.f};
            if (agr < M) v = *reinterpret_cast<const float4*>(ap + kq * 4);
            As[kq * 4 + 0][arow] = v.x;
            As[kq * 4 + 1][arow] = v.y;
            As[kq * 4 + 2][arow] = v.z;
            As[kq * 4 + 3][arow] = v.w;
        }
        #pragma unroll
        for (int q = 0; q < 2; ++q) {
            int c = 2 * t + q;
            int bk = c >> 4, nq = c & 15;
            int gc = colBase + nq * 4;
            const float* bp = B + (size_t)(k0 + bk) * Nc + gc;
            float4 v;
            if (gc + 3 < Nc) {
                v = *reinterpret_cast<const float4*>(bp);
            } else {
                v.x = (gc + 0 < Nc) ? bp[0] : 0.f;
                v.y = (gc + 1 < Nc) ? bp[1] : 0.f;
                v.z = (gc + 2 < Nc) ? bp[2] : 0.f;
                v.w = (gc + 3 < Nc) ? bp[3] : 0.f;
            }
            *reinterpret_cast<float4*>(&Bs[bk][nq * 4]) = v;
        }
        __syncthreads();
        #pragma unroll
        for (int kk = 0; kk < GBK; ++kk) {
            float4 a0 = *reinterpret_cast<const float4*>(&As[kk][ty * 8]);
            float4 a1 = *reinterpret_cast<const float4*>(&As[kk][ty * 8 + 4]);
            float4 b0 = *reinterpret_cast<const float4*>(&Bs[kk][tx * 4]);
            float av[8] = {a0.x, a0.y, a0.z, a0.w, a1.x, a1.y, a1.z, a1.w};
            float bv[4] = {b0.x, b0.y, b0.z, b0.w};
            #pragma unroll
            for (int i = 0; i < 8; ++i)
                #pragma unroll
                for (int j = 0; j < 4; ++j)
                    acc[i][j] += av[i] * bv[j];
        }
        __syncthreads();
    }
    #pragma unroll
    for (int i = 0; i < 8; ++i) {
        int gr = rowBase + ty * 8 + i;
        if (gr >= M) continue;
        int gc0 = colBase + tx * 4;
        float4 v;
        v.x = acc[i][0]; v.y = acc[i][1]; v.z = acc[i][2]; v.w = acc[i][3];
        if (bias) {
            v.x += bias[gc0 + 0]; v.y += (gc0 + 1 < Nc) ? bias[gc0 + 1] : 0.f;
            v.z += (gc0 + 2 < Nc) ? bias[gc0 + 2] : 0.f;
            v.w += (gc0 + 3 < Nc) ? bias[gc0 + 3] : 0.f;
        }
        if (gc0 + 3 < Nc) {
            *reinterpret_cast<float4*>(C + (size_t)gr * Nc + gc0) = v;
        } else {
            float vv[4] = {v.x, v.y, v.z, v.w};
            for (int j = 0; j < 4; ++j)
                if (gc0 + j < Nc) C[(size_t)gr * Nc + gc0 + j] = vv[j];
        }
    }
}

// ---------------- per-node attention coefficients ----------------
__global__ void k_alpha(const float* __restrict__ xh,
                        const float* __restrict__ a_src,
                        const float* __restrict__ a_dst,
                        float* __restrict__ alpha_s,
                        float* __restrict__ alpha_d) {
    int idx = blockIdx.x * 256 + threadIdx.x;   // n*8 + h
    if (idx >= NNODES * NHEAD) return;
    int node = idx >> 3, h = idx & 7;
    const float4* p  = reinterpret_cast<const float4*>(xh + (size_t)node * HHD + h * HDIM);
    const float4* ps = reinterpret_cast<const float4*>(a_src + h * HDIM);
    const float4* pd = reinterpret_cast<const float4*>(a_dst + h * HDIM);
    float ss = 0.f, sd = 0.f;
    #pragma unroll
    for (int q = 0; q < 8; ++q) {
        float4 v = p[q], s4 = ps[q], d4 = pd[q];
        ss += v.x * s4.x + v.y * s4.y + v.z * s4.z + v.w * s4.w;
        sd += v.x * d4.x + v.y * d4.y + v.z * d4.z + v.w * d4.w;
    }
    alpha_s[idx] = ss;
    alpha_d[idx] = sd;
}

// ---------------- GAT aggregation: one wave per node, online softmax -------
__global__ __launch_bounds__(256) void k_agg(const float* __restrict__ xh,
                                             const float* __restrict__ alpha_s,
                                             const float* __restrict__ alpha_d,
                                             const int* __restrict__ row_ptr,
                                             const int* __restrict__ esrc,
                                             const float* __restrict__ bias,
                                             float* __restrict__ out) {
    int node = blockIdx.x * 4 + (threadIdx.x >> 6);
    if (node >= NNODES) return;
    int lane = threadIdx.x & 63;     // lane covers dims [4*lane, 4*lane+3]
    int h = lane >> 3;               // head of this dim chunk
    int beg = row_ptr[node], end = row_ptr[node + 1];
    float ad = alpha_d[node * NHEAD + h];
    float m = -1e30f, s = 0.f;
    float ax = 0.f, ay = 0.f, az = 0.f, aw = 0.f;
    for (int i = beg; i < end; ++i) {
        int src = esrc[i];
        float e = alpha_s[src * NHEAD + h] + ad;
        e = (e > 0.f) ? e : NEG_SLOPE * e;
        float mn = fmaxf(m, e);
        float scale = __expf(m - mn);     // first iter: exp(-inf) -> 0
        float p = __expf(e - mn);
        float4 v = *reinterpret_cast<const float4*>(xh + (size_t)src * HHD + lane * 4);
        s  = s  * scale + p;
        ax = ax * scale + p * v.x;
        ay = ay * scale + p * v.y;
        az = az * scale + p * v.z;
        aw = aw * scale + p * v.w;
        m = mn;
    }
    float inv = 1.f / s;
    float4 b4 = *reinterpret_cast<const float4*>(bias + lane * 4);
    float4 r;
    r.x = fmaxf(ax * inv + b4.x, 0.f);
    r.y = fmaxf(ay * inv + b4.y, 0.f);
    r.z = fmaxf(az * inv + b4.z, 0.f);
    r.w = fmaxf(aw * inv + b4.w, 0.f);
    *reinterpret_cast<float4*>(out + (size_t)node * HHD + lane * 4) = r;
}

// ---------------- launch ----------------

extern "C" void kernel_launch(void* const* d_in, const int* in_sizes, int n_in,
                              void* d_out, int out_size, void* d_ws, size_t ws_size,
                              hipStream_t stream) {
    const float* x   = (const float*)d_in[0];
    const int*   ei  = (const int*)  d_in[1];
    const float* W1  = (const float*)d_in[2];
    const float* a1s = (const float*)d_in[3];
    const float* a1d = (const float*)d_in[4];
    const float* b1  = (const float*)d_in[5];
    const float* W2  = (const float*)d_in[6];
    const float* a2s = (const float*)d_in[7];
    const float* a2d = (const float*)d_in[8];
    const float* b2  = (const float*)d_in[9];
    const float* Wc  = (const float*)d_in[10];
    const float* bc  = (const float*)d_in[11];
    float* out = (float*)d_out;

    char* ws = (char*)d_ws;
    size_t off = 0;
    auto alloc = [&](size_t bytes) -> void* {
        void* p = ws + off;
        off += (bytes + 255) & ~(size_t)255;
        return p;
    };
    float* xh    = (float*)alloc((size_t)NNODES * HHD * 4);
    float* hbuf  = (float*)alloc((size_t)NNODES * HHD * 4);
    float* as_   = (float*)alloc((size_t)NNODES * NHEAD * 4);
    float* ad_   = (float*)alloc((size_t)NNODES * NHEAD * 4);
    int* counts  = (int*)alloc((size_t)NNODES * 4);
    int* row_ptr = (int*)alloc((size_t)(NNODES + 1) * 4);
    int* cursor  = (int*)alloc((size_t)NNODES * 4);
    int* esrc    = (int*)alloc((size_t)NTOT * 4);
    int* bsums   = (int*)alloc(256 * 4);
    int* boff    = (int*)alloc(256 * 4);
    (void)ws_size; (void)in_sizes; (void)n_in; (void)out_size;

    int gn = (NNODES + 255) / 256;   // 196 blocks
    int ge = (NEDGES + 255) / 256;

    // CSR build (same graph for both layers)
    k_init_counts<<<gn, 256, 0, stream>>>(counts);
    k_count<<<ge, 256, 0, stream>>>(ei, counts);
    k_scan1<<<gn, 256, 0, stream>>>(counts, row_ptr, bsums);
    k_scan2<<<1, 256, 0, stream>>>(bsums, boff, gn);
    k_scan3<<<gn, 256, 0, stream>>>(row_ptr, boff, cursor);
    k_scatter<<<ge, 256, 0, stream>>>(ei, cursor, esrc);
    k_scatter_loops<<<gn, 256, 0, stream>>>(cursor, esrc);

    dim3 gHid(HHD / GBN, (NNODES + GBM - 1) / GBM);          // (4, 391)
    dim3 gCls((NCLS + GBN - 1) / GBN, (NNODES + GBM - 1) / GBM); // (1, 391)
    int ga = (NNODES * NHEAD + 255) / 256;
    int gagg = (NNODES + 3) / 4;

    // layer 1
    k_gemm<<<gHid, 256, 0, stream>>>(x, W1, nullptr, xh, NNODES, HHD, 128);
    k_alpha<<<ga, 256, 0, stream>>>(xh, a1s, a1d, as_, ad_);
    k_agg<<<gagg, 256, 0, stream>>>(xh, as_, ad_, row_ptr, esrc, b1, hbuf);

    // layer 2
    k_gemm<<<gHid, 256, 0, stream>>>(hbuf, W2, nullptr, xh, NNODES, HHD, HHD);
    k_alpha<<<ga, 256, 0, stream>>>(xh, a2s, a2d, as_, ad_);
    k_agg<<<gagg, 256, 0, stream>>>(xh, as_, ad_, row_ptr, esrc, b2, hbuf);

    // classifier
    k_gemm<<<gCls, 256, 0, stream>>>(hbuf, Wc, bc, out, NNODES, NCLS, HHD);
}

// Round 3
// 459.994 us; speedup vs baseline: 2.3197x; 1.2790x over previous
//
#include <hip/hip_runtime.h>
#include <math.h>

#define NNODES 50000
#define NEDGES 800000
#define NTOT   850000   // edges + self-loops
#define NHEAD  8
#define HDIM   32
#define HHD    256      // NHEAD*HDIM
#define NCLS   40
#define NEG_SLOPE 0.2f

typedef _Float16 half4 __attribute__((ext_vector_type(4)));

// ---------------- CSR build ----------------

__global__ void k_init_counts(int* __restrict__ counts) {
    int i = blockIdx.x * 256 + threadIdx.x;
    if (i < NNODES) counts[i] = 1;   // self-loop
}

__global__ void k_count(const int* __restrict__ ei, int* __restrict__ counts) {
    int i = blockIdx.x * 256 + threadIdx.x;
    if (i < NEDGES) atomicAdd(&counts[ei[NEDGES + i]], 1);  // dst row
}

__global__ __launch_bounds__(256) void k_scan1(const int* __restrict__ counts,
                                               int* __restrict__ partial,
                                               int* __restrict__ bsums) {
    __shared__ int lds[256];
    int t = threadIdx.x;
    int i = blockIdx.x * 256 + t;
    int v = (i < NNODES) ? counts[i] : 0;
    lds[t] = v;
    __syncthreads();
    for (int off = 1; off < 256; off <<= 1) {
        int add = (t >= off) ? lds[t - off] : 0;
        __syncthreads();
        lds[t] += add;
        __syncthreads();
    }
    if (i < NNODES) partial[i] = lds[t] - v;   // exclusive within block
    if (t == 255) bsums[blockIdx.x] = lds[255];
}

__global__ __launch_bounds__(256) void k_scan2(const int* __restrict__ bsums,
                                               int* __restrict__ boff, int nb) {
    __shared__ int lds[256];
    int t = threadIdx.x;
    int v = (t < nb) ? bsums[t] : 0;
    lds[t] = v;
    __syncthreads();
    for (int off = 1; off < 256; off <<= 1) {
        int add = (t >= off) ? lds[t - off] : 0;
        __syncthreads();
        lds[t] += add;
        __syncthreads();
    }
    if (t < nb) boff[t] = lds[t] - v;
}

__global__ void k_scan3(int* __restrict__ row_ptr, const int* __restrict__ boff,
                        int* __restrict__ cursor) {
    int i = blockIdx.x * 256 + threadIdx.x;
    if (i < NNODES) {
        int r = row_ptr[i] + boff[blockIdx.x];
        row_ptr[i] = r;
        cursor[i] = r;
    }
    if (i == 0) row_ptr[NNODES] = NTOT;   // total edge count is static
}

__global__ void k_scatter(const int* __restrict__ ei, int* __restrict__ cursor,
                          int* __restrict__ esrc) {
    int i = blockIdx.x * 256 + threadIdx.x;
    if (i < NEDGES) {
        int s = ei[i];
        int d = ei[NEDGES + i];
        int pos = atomicAdd(&cursor[d], 1);
        esrc[pos] = s;
    }
}

__global__ void k_scatter_loops(int* __restrict__ cursor, int* __restrict__ esrc) {
    int i = blockIdx.x * 256 + threadIdx.x;
    if (i < NNODES) {
        int pos = atomicAdd(&cursor[i], 1);
        esrc[pos] = i;
    }
}

// ---------------- GEMM (fp32, 128x64 tile, BK=32, LDS-transposed A) --------
// Writes either fp32 (+bias) to Cf or fp16 (raw) to Ch.
#define GBM 128
#define GBN 64
#define GBK 32

__global__ __launch_bounds__(256) void k_gemm(const float* __restrict__ A,
                                              const float* __restrict__ B,
                                              const float* __restrict__ bias,
                                              float* __restrict__ Cf,
                                              _Float16* __restrict__ Ch,
                                              int M, int Nc, int K) {
    __shared__ float As[GBK][132];   // transposed: As[k][m]
    __shared__ float Bs[GBK][68];    // Bs[k][n]
    int t = threadIdx.x;
    int tx = t & 15;                 // col group (tx*4)
    int ty = t >> 4;                 // row group (ty*8)
    int rowBase = blockIdx.y * GBM;
    int colBase = blockIdx.x * GBN;
    float acc[8][4] = {};
    int arow = (t * 4) >> 3;
    int akq  = (t * 4) & 7;
    int agr  = rowBase + arow;
    for (int k0 = 0; k0 < K; k0 += GBK) {
        const float* ap = A + (size_t)agr * K + k0;
        #pragma unroll
        for (int q = 0; q < 4; ++q) {
            int kq = akq + q;
            float4 v = {0.f, 0.f, 0.f, 0.f};
            if (agr < M) v = *reinterpret_cast<const float4*>(ap + kq * 4);
            As[kq * 4 + 0][arow] = v.x;
            As[kq * 4 + 1][arow] = v.y;
            As[kq * 4 + 2][arow] = v.z;
            As[kq * 4 + 3][arow] = v.w;
        }
        #pragma unroll
        for (int q = 0; q < 2; ++q) {
            int c = 2 * t + q;
            int bk = c >> 4, nq = c & 15;
            int gc = colBase + nq * 4;
            const float* bp = B + (size_t)(k0 + bk) * Nc + gc;
            float4 v;
            if (gc + 3 < Nc) {
                v = *reinterpret_cast<const float4*>(bp);
            } else {
                v.x = (gc + 0 < Nc) ? bp[0] : 0.f;
                v.y = (gc + 1 < Nc) ? bp[1] : 0.f;
                v.z = (gc + 2 < Nc) ? bp[2] : 0.f;
                v.w = (gc + 3 < Nc) ? bp[3] : 0.f;
            }
            *reinterpret_cast<float4*>(&Bs[bk][nq * 4]) = v;
        }
        __syncthreads();
        #pragma unroll
        for (int kk = 0; kk < GBK; ++kk) {
            float4 a0 = *reinterpret_cast<const float4*>(&As[kk][ty * 8]);
            float4 a1 = *reinterpret_cast<const float4*>(&As[kk][ty * 8 + 4]);
            float4 b0 = *reinterpret_cast<const float4*>(&Bs[kk][tx * 4]);
            float av[8] = {a0.x, a0.y, a0.z, a0.w, a1.x, a1.y, a1.z, a1.w};
            float bv[4] = {b0.x, b0.y, b0.z, b0.w};
            #pragma unroll
            for (int i = 0; i < 8; ++i)
                #pragma unroll
                for (int j = 0; j < 4; ++j)
                    acc[i][j] += av[i] * bv[j];
        }
        __syncthreads();
    }
    #pragma unroll
    for (int i = 0; i < 8; ++i) {
        int gr = rowBase + ty * 8 + i;
        if (gr >= M) continue;
        int gc0 = colBase + tx * 4;
        if (Ch) {
            // fp16 raw output (full tiles only in this path: Nc == HHD)
            half4 hv;
            hv.x = (_Float16)acc[i][0];
            hv.y = (_Float16)acc[i][1];
            hv.z = (_Float16)acc[i][2];
            hv.w = (_Float16)acc[i][3];
            *reinterpret_cast<half4*>(Ch + (size_t)gr * Nc + gc0) = hv;
        } else {
            float4 v;
            v.x = acc[i][0]; v.y = acc[i][1]; v.z = acc[i][2]; v.w = acc[i][3];
            if (bias) {
                v.x += bias[gc0 + 0];
                v.y += (gc0 + 1 < Nc) ? bias[gc0 + 1] : 0.f;
                v.z += (gc0 + 2 < Nc) ? bias[gc0 + 2] : 0.f;
                v.w += (gc0 + 3 < Nc) ? bias[gc0 + 3] : 0.f;
            }
            if (gc0 + 3 < Nc) {
                *reinterpret_cast<float4*>(Cf + (size_t)gr * Nc + gc0) = v;
            } else {
                float vv[4] = {v.x, v.y, v.z, v.w};
                for (int j = 0; j < 4; ++j)
                    if (gc0 + j < Nc) Cf[(size_t)gr * Nc + gc0 + j] = vv[j];
            }
        }
    }
}

// ---------------- per-node attention coefficients (fp16 features) ----------
__global__ void k_alpha(const _Float16* __restrict__ xh,
                        const float* __restrict__ a_src,
                        const float* __restrict__ a_dst,
                        float* __restrict__ alpha_s,
                        float* __restrict__ alpha_d) {
    int idx = blockIdx.x * 256 + threadIdx.x;   // n*8 + h
    if (idx >= NNODES * NHEAD) return;
    int node = idx >> 3, h = idx & 7;
    const half4* p  = reinterpret_cast<const half4*>(xh + (size_t)node * HHD + h * HDIM);
    const float4* ps = reinterpret_cast<const float4*>(a_src + h * HDIM);
    const float4* pd = reinterpret_cast<const float4*>(a_dst + h * HDIM);
    float ss = 0.f, sd = 0.f;
    #pragma unroll
    for (int q = 0; q < 8; ++q) {
        half4 hv = p[q];
        float4 s4 = ps[q], d4 = pd[q];
        float vx = (float)hv.x, vy = (float)hv.y, vz = (float)hv.z, vw = (float)hv.w;
        ss += vx * s4.x + vy * s4.y + vz * s4.z + vw * s4.w;
        sd += vx * d4.x + vy * d4.y + vz * d4.z + vw * d4.w;
    }
    alpha_s[idx] = ss;
    alpha_d[idx] = sd;
}

// ---------------- GAT aggregation: one wave per node, online softmax -------
__global__ __launch_bounds__(256) void k_agg(const _Float16* __restrict__ xh,
                                             const float* __restrict__ alpha_s,
                                             const float* __restrict__ alpha_d,
                                             const int* __restrict__ row_ptr,
                                             const int* __restrict__ esrc,
                                             const float* __restrict__ bias,
                                             float* __restrict__ out) {
    int node = blockIdx.x * 4 + (threadIdx.x >> 6);
    if (node >= NNODES) return;
    int lane = threadIdx.x & 63;     // lane covers dims [4*lane, 4*lane+3]
    int h = lane >> 3;               // head of this dim chunk
    int beg = row_ptr[node], end = row_ptr[node + 1];
    float ad = alpha_d[node * NHEAD + h];
    float m = -1e30f, s = 0.f;
    float ax = 0.f, ay = 0.f, az = 0.f, aw = 0.f;
    #pragma unroll 2
    for (int i = beg; i < end; ++i) {
        int src = esrc[i];
        float e = alpha_s[src * NHEAD + h] + ad;
        e = (e > 0.f) ? e : NEG_SLOPE * e;
        float mn = fmaxf(m, e);
        float scale = __expf(m - mn);     // first iter: exp(-inf) -> 0
        float p = __expf(e - mn);
        half4 hv = *reinterpret_cast<const half4*>(xh + (size_t)src * HHD + lane * 4);
        s  = s  * scale + p;
        ax = ax * scale + p * (float)hv.x;
        ay = ay * scale + p * (float)hv.y;
        az = az * scale + p * (float)hv.z;
        aw = aw * scale + p * (float)hv.w;
        m = mn;
    }
    float inv = 1.f / s;
    float4 b4 = *reinterpret_cast<const float4*>(bias + lane * 4);
    float4 r;
    r.x = fmaxf(ax * inv + b4.x, 0.f);
    r.y = fmaxf(ay * inv + b4.y, 0.f);
    r.z = fmaxf(az * inv + b4.z, 0.f);
    r.w = fmaxf(aw * inv + b4.w, 0.f);
    *reinterpret_cast<float4*>(out + (size_t)node * HHD + lane * 4) = r;
}

// ---------------- launch ----------------

extern "C" void kernel_launch(void* const* d_in, const int* in_sizes, int n_in,
                              void* d_out, int out_size, void* d_ws, size_t ws_size,
                              hipStream_t stream) {
    const float* x   = (const float*)d_in[0];
    const int*   ei  = (const int*)  d_in[1];
    const float* W1  = (const float*)d_in[2];
    const float* a1s = (const float*)d_in[3];
    const float* a1d = (const float*)d_in[4];
    const float* b1  = (const float*)d_in[5];
    const float* W2  = (const float*)d_in[6];
    const float* a2s = (const float*)d_in[7];
    const float* a2d = (const float*)d_in[8];
    const float* b2  = (const float*)d_in[9];
    const float* Wc  = (const float*)d_in[10];
    const float* bc  = (const float*)d_in[11];
    float* out = (float*)d_out;

    char* ws = (char*)d_ws;
    size_t off = 0;
    auto alloc = [&](size_t bytes) -> void* {
        void* p = ws + off;
        off += (bytes + 255) & ~(size_t)255;
        return p;
    };
    _Float16* xh_h = (_Float16*)alloc((size_t)NNODES * HHD * 2);  // fp16 features
    float* hbuf  = (float*)alloc((size_t)NNODES * HHD * 4);       // fp32 layer out
    float* as_   = (float*)alloc((size_t)NNODES * NHEAD * 4);
    float* ad_   = (float*)alloc((size_t)NNODES * NHEAD * 4);
    int* counts  = (int*)alloc((size_t)NNODES * 4);
    int* row_ptr = (int*)alloc((size_t)(NNODES + 1) * 4);
    int* cursor  = (int*)alloc((size_t)NNODES * 4);
    int* esrc    = (int*)alloc((size_t)NTOT * 4);
    int* bsums   = (int*)alloc(256 * 4);
    int* boff    = (int*)alloc(256 * 4);
    (void)ws_size; (void)in_sizes; (void)n_in; (void)out_size;

    int gn = (NNODES + 255) / 256;   // 196 blocks
    int ge = (NEDGES + 255) / 256;

    // CSR build (same graph for both layers)
    k_init_counts<<<gn, 256, 0, stream>>>(counts);
    k_count<<<ge, 256, 0, stream>>>(ei, counts);
    k_scan1<<<gn, 256, 0, stream>>>(counts, row_ptr, bsums);
    k_scan2<<<1, 256, 0, stream>>>(bsums, boff, gn);
    k_scan3<<<gn, 256, 0, stream>>>(row_ptr, boff, cursor);
    k_scatter<<<ge, 256, 0, stream>>>(ei, cursor, esrc);
    k_scatter_loops<<<gn, 256, 0, stream>>>(cursor, esrc);

    dim3 gHid(HHD / GBN, (NNODES + GBM - 1) / GBM);              // (4, 391)
    dim3 gCls((NCLS + GBN - 1) / GBN, (NNODES + GBM - 1) / GBM); // (1, 391)
    int ga = (NNODES * NHEAD + 255) / 256;
    int gagg = (NNODES + 3) / 4;

    // layer 1
    k_gemm<<<gHid, 256, 0, stream>>>(x, W1, nullptr, nullptr, xh_h, NNODES, HHD, 128);
    k_alpha<<<ga, 256, 0, stream>>>(xh_h, a1s, a1d, as_, ad_);
    k_agg<<<gagg, 256, 0, stream>>>(xh_h, as_, ad_, row_ptr, esrc, b1, hbuf);

    // layer 2
    k_gemm<<<gHid, 256, 0, stream>>>(hbuf, W2, nullptr, nullptr, xh_h, NNODES, HHD, HHD);
    k_alpha<<<ga, 256, 0, stream>>>(xh_h, a2s, a2d, as_, ad_);
    k_agg<<<gagg, 256, 0, stream>>>(xh_h, as_, ad_, row_ptr, esrc, b2, hbuf);

    // classifier
    k_gemm<<<gCls, 256, 0, stream>>>(hbuf, Wc, bc, out, nullptr, NNODES, NCLS, HHD);
}

// Round 4
// 407.886 us; speedup vs baseline: 2.6161x; 1.1278x over previous
//
#include <hip/hip_runtime.h>
#include <math.h>

#define NNODES 50000
#define NEDGES 800000
#define NTOT   850000   // edges + self-loops
#define NHEAD  8
#define HDIM   32
#define HHD    256      // NHEAD*HDIM
#define NCLS   40
#define NEG_SLOPE 0.2f

typedef _Float16 half4 __attribute__((ext_vector_type(4)));
typedef short bf16x8 __attribute__((ext_vector_type(8)));
typedef float f32x16 __attribute__((ext_vector_type(16)));
typedef unsigned short u16;

__device__ __forceinline__ u16 f2bf(float x) {
    union { float f; unsigned u; } c; c.f = x;
    return (u16)(c.u >> 16);          // truncation split keeps lo exact-ish
}
__device__ __forceinline__ float bf2f(u16 h) {
    union { unsigned u; float f; } c; c.u = ((unsigned)h) << 16;
    return c.f;
}

// ---------------- CSR build ----------------

__global__ void k_init_counts(int* __restrict__ counts) {
    int i = blockIdx.x * 256 + threadIdx.x;
    if (i < NNODES) counts[i] = 1;   // self-loop
}

__global__ void k_count(const int* __restrict__ ei, int* __restrict__ counts) {
    int i = blockIdx.x * 256 + threadIdx.x;
    if (i < NEDGES) atomicAdd(&counts[ei[NEDGES + i]], 1);  // dst row
}

__global__ __launch_bounds__(256) void k_scan1(const int* __restrict__ counts,
                                               int* __restrict__ partial,
                                               int* __restrict__ bsums) {
    __shared__ int lds[256];
    int t = threadIdx.x;
    int i = blockIdx.x * 256 + t;
    int v = (i < NNODES) ? counts[i] : 0;
    lds[t] = v;
    __syncthreads();
    for (int off = 1; off < 256; off <<= 1) {
        int add = (t >= off) ? lds[t - off] : 0;
        __syncthreads();
        lds[t] += add;
        __syncthreads();
    }
    if (i < NNODES) partial[i] = lds[t] - v;   // exclusive within block
    if (t == 255) bsums[blockIdx.x] = lds[255];
}

__global__ __launch_bounds__(256) void k_scan2(const int* __restrict__ bsums,
                                               int* __restrict__ boff, int nb) {
    __shared__ int lds[256];
    int t = threadIdx.x;
    int v = (t < nb) ? bsums[t] : 0;
    lds[t] = v;
    __syncthreads();
    for (int off = 1; off < 256; off <<= 1) {
        int add = (t >= off) ? lds[t - off] : 0;
        __syncthreads();
        lds[t] += add;
        __syncthreads();
    }
    if (t < nb) boff[t] = lds[t] - v;
}

__global__ void k_scan3(int* __restrict__ row_ptr, const int* __restrict__ boff,
                        int* __restrict__ cursor) {
    int i = blockIdx.x * 256 + threadIdx.x;
    if (i < NNODES) {
        int r = row_ptr[i] + boff[blockIdx.x];
        row_ptr[i] = r;
        cursor[i] = r;
    }
    if (i == 0) row_ptr[NNODES] = NTOT;   // total edge count is static
}

__global__ void k_scatter(const int* __restrict__ ei, int* __restrict__ cursor,
                          int* __restrict__ esrc) {
    int i = blockIdx.x * 256 + threadIdx.x;
    if (i < NEDGES) {
        int s = ei[i];
        int d = ei[NEDGES + i];
        int pos = atomicAdd(&cursor[d], 1);
        esrc[pos] = s;
    }
}

__global__ void k_scatter_loops(int* __restrict__ cursor, int* __restrict__ esrc) {
    int i = blockIdx.x * 256 + threadIdx.x;
    if (i < NNODES) {
        int pos = atomicAdd(&cursor[i], 1);
        esrc[pos] = i;
    }
}

// ---------------- weight prep: transpose + bf16 hi/lo split ----------------
// W[K,Nc] fp32 -> Bt_hi/Bt_lo [Npad][K] bf16 (k-contiguous rows)
__global__ void k_prep_w(const float* __restrict__ W, u16* __restrict__ Bt_hi,
                         u16* __restrict__ Bt_lo, int K, int Nc, int Npad) {
    int idx = blockIdx.x * 256 + threadIdx.x;   // n*K + k
    if (idx >= Npad * K) return;
    int n = idx / K, k = idx - n * K;
    float w = (n < Nc) ? W[(size_t)k * Nc + n] : 0.f;
    u16 h = f2bf(w);
    float lo = w - bf2f(h);
    Bt_hi[idx] = h;
    Bt_lo[idx] = f2bf(lo);
}

// ---------------- MFMA split-bf16 GEMM ----------------
// C[M,Nc] = A[M,K](fp32) @ B[K,Nc], B pre-split/transposed.
// Hidden path: Ch = fp16 raw (no bias). Classifier: Cf = fp32 + bias, col<NcReal.
#define TBM 128
#define TBN 128
#define TBK 32
#define APAD 40   // LDS row stride in bf16 elems (80 B: 5r mod 32 -> conflict-free)

__global__ __launch_bounds__(256) void k_mfma_gemm(
    const float* __restrict__ A,
    const u16* __restrict__ Bt_hi,
    const u16* __restrict__ Bt_lo,
    const float* __restrict__ bias,
    _Float16* __restrict__ Ch,
    float* __restrict__ Cf,
    int M, int K, int NcReal, int ldc)
{
    __shared__ u16 Ahi[TBM][APAD];
    __shared__ u16 Alo[TBM][APAD];
    int t = threadIdx.x;
    int lane = t & 63;
    int wid = t >> 6;
    int wr = wid >> 1, wc = wid & 1;            // 2x2 wave grid
    int rowBase = blockIdx.y * TBM;
    int colBase = blockIdx.x * TBN;

    // A staging: thread t loads row t>>1, 16 contiguous k at offset (t&1)*16
    int arow = t >> 1;
    int akoff = (t & 1) * 16;
    bool arow_ok = (rowBase + arow) < M;
    const float* aptr = A + (size_t)(rowBase + arow) * K + akoff;

    f32x16 acc[2][2];
    #pragma unroll
    for (int i = 0; i < 2; ++i)
        #pragma unroll
        for (int j = 0; j < 2; ++j)
            #pragma unroll
            for (int r = 0; r < 16; ++r) acc[i][j][r] = 0.f;

    float4 areg[4];
    #pragma unroll
    for (int i = 0; i < 4; ++i)
        areg[i] = arow_ok ? *reinterpret_cast<const float4*>(aptr + i * 4)
                          : float4{0.f, 0.f, 0.f, 0.f};

    for (int k0 = 0; k0 < K; k0 += TBK) {
        // ---- write staged regs to LDS as hi/lo bf16 ----
        #pragma unroll
        for (int i = 0; i < 4; ++i) {
            float vv[4] = {areg[i].x, areg[i].y, areg[i].z, areg[i].w};
            u16 h[4], l[4];
            #pragma unroll
            for (int c = 0; c < 4; ++c) {
                h[c] = f2bf(vv[c]);
                l[c] = f2bf(vv[c] - bf2f(h[c]));
            }
            *reinterpret_cast<uint2*>(&Ahi[arow][akoff + i * 4]) =
                uint2{(unsigned)h[0] | ((unsigned)h[1] << 16),
                      (unsigned)h[2] | ((unsigned)h[3] << 16)};
            *reinterpret_cast<uint2*>(&Alo[arow][akoff + i * 4]) =
                uint2{(unsigned)l[0] | ((unsigned)l[1] << 16),
                      (unsigned)l[2] | ((unsigned)l[3] << 16)};
        }
        __syncthreads();
        // ---- prefetch next K-tile into regs (overlaps MFMA below) ----
        if (k0 + TBK < K) {
            const float* ap = aptr + k0 + TBK;
            #pragma unroll
            for (int i = 0; i < 4; ++i)
                areg[i] = arow_ok ? *reinterpret_cast<const float4*>(ap + i * 4)
                                  : float4{0.f, 0.f, 0.f, 0.f};
        }
        // ---- compute: 2 substeps of K=16 ----
        #pragma unroll
        for (int sub = 0; sub < 2; ++sub) {
            int kfo = sub * 16 + (lane >> 5) * 8;    // element offset in row
            bf16x8 ah[2], al[2];
            #pragma unroll
            for (int rt = 0; rt < 2; ++rt) {
                int r = wr * 64 + rt * 32 + (lane & 31);
                ah[rt] = *reinterpret_cast<const bf16x8*>(&Ahi[r][kfo]);
                al[rt] = *reinterpret_cast<const bf16x8*>(&Alo[r][kfo]);
            }
            bf16x8 bh[2], bl[2];
            #pragma unroll
            for (int ct = 0; ct < 2; ++ct) {
                int n = colBase + wc * 64 + ct * 32 + (lane & 31);
                size_t boff = (size_t)n * K + k0 + kfo;
                bh[ct] = *reinterpret_cast<const bf16x8*>(Bt_hi + boff);
                bl[ct] = *reinterpret_cast<const bf16x8*>(Bt_lo + boff);
            }
            #pragma unroll
            for (int rt = 0; rt < 2; ++rt)
                #pragma unroll
                for (int ct = 0; ct < 2; ++ct) {
                    acc[rt][ct] = __builtin_amdgcn_mfma_f32_32x32x16_bf16(
                        ah[rt], bh[ct], acc[rt][ct], 0, 0, 0);
                    acc[rt][ct] = __builtin_amdgcn_mfma_f32_32x32x16_bf16(
                        ah[rt], bl[ct], acc[rt][ct], 0, 0, 0);
                    acc[rt][ct] = __builtin_amdgcn_mfma_f32_32x32x16_bf16(
                        al[rt], bh[ct], acc[rt][ct], 0, 0, 0);
                }
        }
        __syncthreads();
    }

    // ---- epilogue: C/D layout col=lane&31, row=(r&3)+8*(r>>2)+4*(lane>>5) ----
    #pragma unroll
    for (int rt = 0; rt < 2; ++rt)
        #pragma unroll
        for (int ct = 0; ct < 2; ++ct) {
            int col = colBase + wc * 64 + ct * 32 + (lane & 31);
            #pragma unroll
            for (int r = 0; r < 16; ++r) {
                int row = rowBase + wr * 64 + rt * 32 +
                          (r & 3) + 8 * (r >> 2) + 4 * (lane >> 5);
                if (row >= M) continue;
                float v = acc[rt][ct][r];
                if (Ch) {
                    Ch[(size_t)row * ldc + col] = (_Float16)v;
                } else if (col < NcReal) {
                    Cf[(size_t)row * ldc + col] = v + bias[col];
                }
            }
        }
}

// ---------------- per-node attention coefficients (fp16 features) ----------
__global__ void k_alpha(const _Float16* __restrict__ xh,
                        const float* __restrict__ a_src,
                        const float* __restrict__ a_dst,
                        float* __restrict__ alpha_s,
                        float* __restrict__ alpha_d) {
    int idx = blockIdx.x * 256 + threadIdx.x;   // n*8 + h
    if (idx >= NNODES * NHEAD) return;
    int node = idx >> 3, h = idx & 7;
    const half4* p  = reinterpret_cast<const half4*>(xh + (size_t)node * HHD + h * HDIM);
    const float4* ps = reinterpret_cast<const float4*>(a_src + h * HDIM);
    const float4* pd = reinterpret_cast<const float4*>(a_dst + h * HDIM);
    float ss = 0.f, sd = 0.f;
    #pragma unroll
    for (int q = 0; q < 8; ++q) {
        half4 hv = p[q];
        float4 s4 = ps[q], d4 = pd[q];
        float vx = (float)hv.x, vy = (float)hv.y, vz = (float)hv.z, vw = (float)hv.w;
        ss += vx * s4.x + vy * s4.y + vz * s4.z + vw * s4.w;
        sd += vx * d4.x + vy * d4.y + vz * d4.z + vw * d4.w;
    }
    alpha_s[idx] = ss;
    alpha_d[idx] = sd;
}

// ---------------- GAT aggregation: one wave per node, online softmax -------
__global__ __launch_bounds__(256) void k_agg(const _Float16* __restrict__ xh,
                                             const float* __restrict__ alpha_s,
                                             const float* __restrict__ alpha_d,
                                             const int* __restrict__ row_ptr,
                                             const int* __restrict__ esrc,
                                             const float* __restrict__ bias,
                                             float* __restrict__ out) {
    int node = blockIdx.x * 4 + (threadIdx.x >> 6);
    if (node >= NNODES) return;
    int lane = threadIdx.x & 63;     // lane covers dims [4*lane, 4*lane+3]
    int h = lane >> 3;               // head of this dim chunk
    int beg = row_ptr[node], end = row_ptr[node + 1];
    float ad = alpha_d[node * NHEAD + h];
    float m = -1e30f, s = 0.f;
    float ax = 0.f, ay = 0.f, az = 0.f, aw = 0.f;
    #pragma unroll 2
    for (int i = beg; i < end; ++i) {
        int src = esrc[i];
        float e = alpha_s[src * NHEAD + h] + ad;
        e = (e > 0.f) ? e : NEG_SLOPE * e;
        float mn = fmaxf(m, e);
        float scale = __expf(m - mn);     // first iter: exp(-inf) -> 0
        float p = __expf(e - mn);
        half4 hv = *reinterpret_cast<const half4*>(xh + (size_t)src * HHD + lane * 4);
        s  = s  * scale + p;
        ax = ax * scale + p * (float)hv.x;
        ay = ay * scale + p * (float)hv.y;
        az = az * scale + p * (float)hv.z;
        aw = aw * scale + p * (float)hv.w;
        m = mn;
    }
    float inv = 1.f / s;
    float4 b4 = *reinterpret_cast<const float4*>(bias + lane * 4);
    float4 r;
    r.x = fmaxf(ax * inv + b4.x, 0.f);
    r.y = fmaxf(ay * inv + b4.y, 0.f);
    r.z = fmaxf(az * inv + b4.z, 0.f);
    r.w = fmaxf(aw * inv + b4.w, 0.f);
    *reinterpret_cast<float4*>(out + (size_t)node * HHD + lane * 4) = r;
}

// ---------------- launch ----------------

extern "C" void kernel_launch(void* const* d_in, const int* in_sizes, int n_in,
                              void* d_out, int out_size, void* d_ws, size_t ws_size,
                              hipStream_t stream) {
    const float* x   = (const float*)d_in[0];
    const int*   ei  = (const int*)  d_in[1];
    const float* W1  = (const float*)d_in[2];
    const float* a1s = (const float*)d_in[3];
    const float* a1d = (const float*)d_in[4];
    const float* b1  = (const float*)d_in[5];
    const float* W2  = (const float*)d_in[6];
    const float* a2s = (const float*)d_in[7];
    const float* a2d = (const float*)d_in[8];
    const float* b2  = (const float*)d_in[9];
    const float* Wc  = (const float*)d_in[10];
    const float* bc  = (const float*)d_in[11];
    float* out = (float*)d_out;

    char* ws = (char*)d_ws;
    size_t off = 0;
    auto alloc = [&](size_t bytes) -> void* {
        void* p = ws + off;
        off += (bytes + 255) & ~(size_t)255;
        return p;
    };
    _Float16* xh_h = (_Float16*)alloc((size_t)NNODES * HHD * 2);  // fp16 features
    float* hbuf  = (float*)alloc((size_t)NNODES * HHD * 4);       // fp32 layer out
    float* as_   = (float*)alloc((size_t)NNODES * NHEAD * 4);
    float* ad_   = (float*)alloc((size_t)NNODES * NHEAD * 4);
    int* counts  = (int*)alloc((size_t)NNODES * 4);
    int* row_ptr = (int*)alloc((size_t)(NNODES + 1) * 4);
    int* cursor  = (int*)alloc((size_t)NNODES * 4);
    int* esrc    = (int*)alloc((size_t)NTOT * 4);
    int* bsums   = (int*)alloc(256 * 4);
    int* boff    = (int*)alloc(256 * 4);
    u16* w1t_hi  = (u16*)alloc((size_t)HHD * 128 * 2);   // [256][128]
    u16* w1t_lo  = (u16*)alloc((size_t)HHD * 128 * 2);
    u16* w2t_hi  = (u16*)alloc((size_t)HHD * HHD * 2);   // [256][256]
    u16* w2t_lo  = (u16*)alloc((size_t)HHD * HHD * 2);
    u16* wct_hi  = (u16*)alloc((size_t)TBN * HHD * 2);   // [128][256] zero-padded
    u16* wct_lo  = (u16*)alloc((size_t)TBN * HHD * 2);
    (void)ws_size; (void)in_sizes; (void)n_in; (void)out_size;

    int gn = (NNODES + 255) / 256;   // 196 blocks
    int ge = (NEDGES + 255) / 256;

    // CSR build (same graph for both layers)
    k_init_counts<<<gn, 256, 0, stream>>>(counts);
    k_count<<<ge, 256, 0, stream>>>(ei, counts);
    k_scan1<<<gn, 256, 0, stream>>>(counts, row_ptr, bsums);
    k_scan2<<<1, 256, 0, stream>>>(bsums, boff, gn);
    k_scan3<<<gn, 256, 0, stream>>>(row_ptr, boff, cursor);
    k_scatter<<<ge, 256, 0, stream>>>(ei, cursor, esrc);
    k_scatter_loops<<<gn, 256, 0, stream>>>(cursor, esrc);

    // weight prep (transpose + hi/lo split)
    k_prep_w<<<(HHD * 128 + 255) / 256, 256, 0, stream>>>(W1, w1t_hi, w1t_lo, 128, HHD, HHD);
    k_prep_w<<<(HHD * HHD + 255) / 256, 256, 0, stream>>>(W2, w2t_hi, w2t_lo, HHD, HHD, HHD);
    k_prep_w<<<(TBN * HHD + 255) / 256, 256, 0, stream>>>(Wc, wct_hi, wct_lo, HHD, NCLS, TBN);

    dim3 gHid(HHD / TBN, (NNODES + TBM - 1) / TBM);   // (2, 391)
    dim3 gCls(1, (NNODES + TBM - 1) / TBM);           // (1, 391)
    int ga = (NNODES * NHEAD + 255) / 256;
    int gagg = (NNODES + 3) / 4;

    // layer 1
    k_mfma_gemm<<<gHid, 256, 0, stream>>>(x, w1t_hi, w1t_lo, nullptr, xh_h, nullptr,
                                          NNODES, 128, HHD, HHD);
    k_alpha<<<ga, 256, 0, stream>>>(xh_h, a1s, a1d, as_, ad_);
    k_agg<<<gagg, 256, 0, stream>>>(xh_h, as_, ad_, row_ptr, esrc, b1, hbuf);

    // layer 2
    k_mfma_gemm<<<gHid, 256, 0, stream>>>(hbuf, w2t_hi, w2t_lo, nullptr, xh_h, nullptr,
                                          NNODES, HHD, HHD, HHD);
    k_alpha<<<ga, 256, 0, stream>>>(xh_h, a2s, a2d, as_, ad_);
    k_agg<<<gagg, 256, 0, stream>>>(xh_h, as_, ad_, row_ptr, esrc, b2, hbuf);

    // classifier
    k_mfma_gemm<<<gCls, 256, 0, stream>>>(hbuf, wct_hi, wct_lo, bc, nullptr, out,
                                          NNODES, HHD, NCLS, NCLS);
}